// Round 1
// baseline (101.809 us; speedup 1.0000x reference)
//
#include <hip/hip_runtime.h>
#include <math.h>

typedef _Float16 v8h __attribute__((ext_vector_type(8)));
typedef float    v4f __attribute__((ext_vector_type(4)));

// LDS layout (65536 B):
//  B16 [0, 32768): 128 rows x 128 fp16 (256 B rows, XOR-swizzled 16B chunks)
//      rows 0..95  = ref halo (8x12, zero rows for OOB -> exact zero-pad semantics)
//      rows 96..127 = main pixel rows (fp16 hi) == A_hi
//      REUSED in epoch 3/4 as VT: rows = value-channel, cols = position 0..127
//  ALO [32768, 40960): 32 x 128 fp16 = lo part of main (fp16 hi/lo split)
//  L   [40960, 57344): 32 x 128 fp32 logits
//  P   [57344, 65536): 32 x 128 fp16 attn matrix (zero except 26 cols/row)
#define B_OFF   0
#define ALO_OFF 32768
#define L_OFF   40960
#define P_OFF   57344

// byte offset of 16B chunk c16 in row r (256 B rows, XOR bank swizzle)
__device__ __forceinline__ int swz(int r, int c16) {
    return (r << 8) + ((c16 ^ (r & 15)) << 4);
}

__global__ __launch_bounds__(512, 4) void local_attn_mfma3(
    const float* __restrict__ main_,
    const float* __restrict__ main_value,
    const float* __restrict__ ref,
    const float* __restrict__ ref_value,
    float* __restrict__ out)
{
    __shared__ __align__(16) char S[65536];

    const int tid = threadIdx.x;
    // XCD-contiguous tile assignment: hardware bid round-robins across 8 XCDs;
    // remap so each XCD owns 64 consecutive logical tiles (half an image ->
    // ref/ref_value slice ~2.4 MB fits the 4 MB per-XCD L2, halo re-reads hit L2).
    // Bijective since 512 % 8 == 0.
    const int bid0 = blockIdx.x;
    const int bid  = ((bid0 & 7) << 6) | (bid0 >> 3);
    const int b  = bid >> 7;
    const int h0 = ((bid >> 3) & 15) << 2;   // 4-row tiles
    const int w0 = (bid & 7) << 3;           // 8-col tiles
    const int lane = tid & 63, w = tid >> 6;

    // ========== epoch 1a: issue A/B staging loads ==========
    const int r = tid >> 2;          // 0..127: B row
    const int q = tid & 3;           // channel quarter (32 ch)
    bool valid = true;
    const float* src;
    if (r < 96) {
        const int hy = r / 12, hx = r - hy * 12;
        const int gh = h0 - 2 + hy, gw = w0 - 2 + hx;
        valid = (gh >= 0) & (gh < 64) & (gw >= 0) & (gw < 64);
        src = ref + (size_t)((((b << 6) + (valid ? gh : 0)) << 6) + (valid ? gw : 0)) * 128;
    } else {
        const int t = r - 96;
        src = main_ + (size_t)((((b << 6) + h0 + (t >> 3)) << 6) + (w0 + (t & 7))) * 128;
    }
    float4 e1[8];
    #pragma unroll
    for (int g = 0; g < 8; ++g)
        e1[g] = valid ? *(const float4*)(src + (q << 5) + (g << 2)) : make_float4(0, 0, 0, 0);

    // ========== epoch 1b: convert + write A/B to LDS, zero P ==========
    #pragma unroll
    for (int g = 0; g < 4; ++g) {
        const float4 v0 = e1[2 * g], v1 = e1[2 * g + 1];
        float a8[8] = {v0.x, v0.y, v0.z, v0.w, v1.x, v1.y, v1.z, v1.w};
        v8h hi;
        #pragma unroll
        for (int j = 0; j < 8; ++j) hi[j] = (_Float16)a8[j];
        *(v8h*)(S + B_OFF + swz(r, (q << 2) + g)) = hi;
        if (r >= 96) {                 // lo part of main (fp16 hi/lo split)
            v8h lo;
            #pragma unroll
            for (int j = 0; j < 8; ++j) lo[j] = (_Float16)(a8[j] - (float)hi[j]);
            *(v8h*)(S + ALO_OFF + swz(r - 96, (q << 2) + g)) = lo;
        }
    }
    *(uint4*)(S + P_OFF + tid * 16) = make_uint4(0, 0, 0, 0);

    // Barrier 1 now drains only the A/B loads (V not yet issued):
    // epoch 2 starts ~T(A) instead of T(A+V).
    __syncthreads();

    const int l15 = lane & 15, quad = lane >> 4;
    const int mt  = w >> 2;              // m-tile (16 pixels)
    const int ntp = (w & 3) << 1;        // first of 2 n-tiles

    // ========== epoch 2a: issue V loads (stream overlaps MFMA below) ==========
    // Issued AFTER barrier 1 so the A-phase gets full BW and the V stream is
    // hidden under epoch-2 MFMA + L-write. Held as f32 until after the MFMAs.
    float pv[4][8];
    #pragma unroll
    for (int i = 0; i < 4; ++i) {
        const int tk = w + (i << 3);              // 0..31 tasks
        const int pb = tk & 15;                   // position block (8 pos)
        const int ch = ((tk >> 4) << 6) + lane;   // value channel 0..127
        #pragma unroll
        for (int j = 0; j < 8; ++j) {
            const int pos = (pb << 3) + j;        // wave-uniform
            float v = 0.f;
            if (pos < 96) {
                const int hy = pos / 12, hx = pos - hy * 12;
                const int gh = h0 - 2 + hy, gw = w0 - 2 + hx;
                if ((gh >= 0) & (gh < 64) & (gw >= 0) & (gw < 64))
                    v = ref_value[(size_t)((((b << 6) + gh) << 6) + gw) * 128 + ch];
            } else {
                const int t2 = pos - 96;
                v = main_value[(size_t)((((b << 6) + h0 + (t2 >> 3)) << 6) + (w0 + (t2 & 7))) * 128 + ch];
            }
            pv[i][j] = v;
        }
    }

    // ========== epoch 2b: L = (A_hi + A_lo) * B^T via MFMA ==========
    {
        const int arow = 96 + (mt << 4) + l15;
        const int lrow = (mt << 4) + l15;
        const int b0r  = (ntp << 4) + l15, b1r = b0r + 16;
        v4f acc0 = {0, 0, 0, 0}, acc1 = {0, 0, 0, 0};
        #pragma unroll
        for (int ks = 0; ks < 4; ++ks) {
            const int c16 = (ks << 2) + quad;
            const v8h ahi = *(const v8h*)(S + B_OFF   + swz(arow, c16));
            const v8h alo = *(const v8h*)(S + ALO_OFF + swz(lrow, c16));
            const v8h bb0 = *(const v8h*)(S + B_OFF   + swz(b0r,  c16));
            const v8h bb1 = *(const v8h*)(S + B_OFF   + swz(b1r,  c16));
            acc0 = __builtin_amdgcn_mfma_f32_16x16x32_f16(ahi, bb0, acc0, 0, 0, 0);
            acc0 = __builtin_amdgcn_mfma_f32_16x16x32_f16(alo, bb0, acc0, 0, 0, 0);
            acc1 = __builtin_amdgcn_mfma_f32_16x16x32_f16(ahi, bb1, acc1, 0, 0, 0);
            acc1 = __builtin_amdgcn_mfma_f32_16x16x32_f16(alo, bb1, acc1, 0, 0, 0);
        }
        // C layout: col = lane&15 (n), row = quad*4 + reg (m)
        #pragma unroll
        for (int j = 0; j < 4; ++j) {
            const int px = (mt << 4) + (quad << 2) + j;
            *(float*)(S + L_OFF + (px << 9) + ((((ntp    ) << 4) + l15) << 2)) = acc0[j];
            *(float*)(S + L_OFF + (px << 9) + ((((ntp + 1) << 4) + l15) << 2)) = acc1[j];
        }
    }

    // convert V to fp16 now (dependency-waits the V stream tail here, after
    // the MFMAs instead of before barrier 1)
    v8h hv[4];
    #pragma unroll
    for (int i = 0; i < 4; ++i)
        #pragma unroll
        for (int j = 0; j < 8; ++j) hv[i][j] = (_Float16)pv[i][j];

    __syncthreads();

    // ========== epoch 3: VT writes (overwrite B16) + softmax -> P ==========
    {
        #pragma unroll
        for (int i = 0; i < 4; ++i) {
            const int tk = w + (i << 3);
            const int pb = tk & 15;
            const int ch = ((tk >> 4) << 6) + lane;
            *(v8h*)(S + B_OFF + swz(ch, pb)) = hv[i];
        }
        // softmax: 2 pixels per wave-half (butterfly stays within 32 lanes)
        const int half = lane >> 5;
        const int l    = lane & 31;
        #pragma unroll
        for (int i = 0; i < 2; ++i) {
            const int t = (w << 2) + (i << 1) + half;
            const int ty = t >> 3, tx = t & 7;
            const bool act = l < 26;
            int col;
            if (l < 25) {
                const int dy = l / 5 - 2, dx = l % 5 - 2;
                col = (ty + dy + 2) * 12 + (tx + dx + 2);
            } else col = 96 + t;                  // self column
            const float lg = act ? *(const float*)(S + L_OFF + (t << 9) + (col << 2)) : -INFINITY;
            float m = lg;
            #pragma unroll
            for (int off = 16; off; off >>= 1) m = fmaxf(m, __shfl_xor(m, off));
            const float e = act ? __expf(lg - m) : 0.f;
            float s = e;
            #pragma unroll
            for (int off = 16; off; off >>= 1) s += __shfl_xor(s, off);
            if (act)
                *(_Float16*)(S + P_OFF + swz(t, col >> 3) + ((col & 7) << 1)) = (_Float16)(e / s);
        }
    }
    __syncthreads();

    // ========== epoch 4: O = P * V via MFMA, store ==========
    {
        const int prow = (mt << 4) + l15;
        const int v0r  = (ntp << 4) + l15, v1r = v0r + 16;   // VT rows = out channels
        v4f acc0 = {0, 0, 0, 0}, acc1 = {0, 0, 0, 0};
        #pragma unroll
        for (int ks = 0; ks < 4; ++ks) {
            const int c16 = (ks << 2) + quad;
            const v8h pa  = *(const v8h*)(S + P_OFF + swz(prow, c16));
            const v8h vt0 = *(const v8h*)(S + B_OFF + swz(v0r,  c16));
            const v8h vt1 = *(const v8h*)(S + B_OFF + swz(v1r,  c16));
            acc0 = __builtin_amdgcn_mfma_f32_16x16x32_f16(pa, vt0, acc0, 0, 0, 0);
            acc1 = __builtin_amdgcn_mfma_f32_16x16x32_f16(pa, vt1, acc1, 0, 0, 0);
        }
        #pragma unroll
        for (int j = 0; j < 4; ++j) {
            const int px = (mt << 4) + (quad << 2) + j;
            const size_t gbase =
                (size_t)((((b << 6) + h0 + (px >> 3)) << 6) + (w0 + (px & 7))) * 128;
            out[gbase + ((ntp    ) << 4) + l15] = acc0[j];
            out[gbase + ((ntp + 1) << 4) + l15] = acc1[j];
        }
    }
}

extern "C" void kernel_launch(void* const* d_in, const int* in_sizes, int n_in,
                              void* d_out, int out_size, void* d_ws, size_t ws_size,
                              hipStream_t stream) {
    const float* main_      = (const float*)d_in[0];
    const float* main_value = (const float*)d_in[1];
    const float* ref        = (const float*)d_in[2];
    const float* ref_value  = (const float*)d_in[3];
    float* out = (float*)d_out;

    dim3 grid(4 * 16 * 8), block(512);   // 512 blocks (4x8 pixel tiles), 2 blocks/CU
    local_attn_mfma3<<<grid, block, 0, stream>>>(main_, main_value, ref, ref_value, out);
}

// Round 2
// 98.191 us; speedup vs baseline: 1.0368x; 1.0368x over previous
//
#include <hip/hip_runtime.h>
#include <math.h>

typedef _Float16 v8h __attribute__((ext_vector_type(8)));
typedef float    v4f __attribute__((ext_vector_type(4)));

// LDS layout (65536 B):
//  B16 [0, 32768): 128 rows x 128 fp16 (256 B rows, XOR-swizzled 16B chunks)
//      rows 0..95  = ref halo (8x12, zero rows for OOB -> exact zero-pad semantics)
//      rows 96..127 = main pixel rows (fp16 hi) == A_hi
//      REUSED in epoch 3/4 as VT: rows = value-channel, cols = position 0..127
//  ALO [32768, 40960): 32 x 128 fp16 = lo part of main (fp16 hi/lo split)
//  L   [40960, 57344): 32 x 128 fp32 logits
//  P   [57344, 65536): 32 x 128 fp16 attn matrix (zero except 26 cols/row)
#define B_OFF   0
#define ALO_OFF 32768
#define L_OFF   40960
#define P_OFF   57344

// byte offset of 16B chunk c16 in row r (256 B rows, XOR bank swizzle)
__device__ __forceinline__ int swz(int r, int c16) {
    return (r << 8) + ((c16 ^ (r & 15)) << 4);
}

__global__ __launch_bounds__(512, 4) void local_attn_mfma4(
    const float* __restrict__ main_,
    const float* __restrict__ main_value,
    const float* __restrict__ ref,
    const float* __restrict__ ref_value,
    float* __restrict__ out)
{
    __shared__ __align__(16) char S[65536];

    const int tid = threadIdx.x;
    // XCD-contiguous tile assignment (ONLY delta vs the 97.8us round-0 kernel):
    // hardware bid round-robins across 8 XCDs; remap so each XCD's ~64
    // co-resident blocks form a contiguous half-image. ref+ref_value slice
    // (36 rows x 64 cols x 128 ch x 2 tensors ~ 2.4 MB) fits the 4 MB per-XCD
    // L2, so the 3x halo re-reads become L2 hits instead of HBM fetches.
    // Bijective since 512 % 8 == 0.
    const int bid0 = blockIdx.x;
    const int bid  = ((bid0 & 7) << 6) | (bid0 >> 3);
    const int b  = bid >> 7;
    const int h0 = ((bid >> 3) & 15) << 2;   // 4-row tiles
    const int w0 = (bid & 7) << 3;           // 8-col tiles
    const int lane = tid & 63, w = tid >> 6;

    // ========== epoch 1a: issue A/B staging loads (oldest in vmcnt queue) ==========
    const int r = tid >> 2;          // 0..127: B row
    const int q = tid & 3;           // channel quarter (32 ch)
    bool valid = true;
    const float* src;
    if (r < 96) {
        const int hy = r / 12, hx = r - hy * 12;
        const int gh = h0 - 2 + hy, gw = w0 - 2 + hx;
        valid = (gh >= 0) & (gh < 64) & (gw >= 0) & (gw < 64);
        src = ref + (size_t)((((b << 6) + (valid ? gh : 0)) << 6) + (valid ? gw : 0)) * 128;
    } else {
        const int t = r - 96;
        src = main_ + (size_t)((((b << 6) + h0 + (t >> 3)) << 6) + (w0 + (t & 7))) * 128;
    }
    float4 e1[8];
    #pragma unroll
    for (int g = 0; g < 8; ++g)
        e1[g] = valid ? *(const float4*)(src + (q << 5) + (g << 2)) : make_float4(0, 0, 0, 0);

    // ========== prefetch V (epoch-3 data) — overlaps epochs 1-2 ==========
    // Issued together with A/B so both streams share the BW-bound memory
    // phase at maximum memory-level parallelism (round-1 lesson: splitting
    // them serializes, total is T(A+V) either way).
    float pv[4][8];
    #pragma unroll
    for (int i = 0; i < 4; ++i) {
        const int tk = w + (i << 3);              // 0..31 tasks
        const int pb = tk & 15;                   // position block (8 pos)
        const int ch = ((tk >> 4) << 6) + lane;   // value channel 0..127
        #pragma unroll
        for (int j = 0; j < 8; ++j) {
            const int pos = (pb << 3) + j;        // wave-uniform
            float v = 0.f;
            if (pos < 96) {
                const int hy = pos / 12, hx = pos - hy * 12;
                const int gh = h0 - 2 + hy, gw = w0 - 2 + hx;
                if ((gh >= 0) & (gh < 64) & (gw >= 0) & (gw < 64))
                    v = ref_value[(size_t)((((b << 6) + gh) << 6) + gw) * 128 + ch];
            } else {
                const int t2 = pos - 96;
                v = main_value[(size_t)((((b << 6) + h0 + (t2 >> 3)) << 6) + (w0 + (t2 & 7))) * 128 + ch];
            }
            pv[i][j] = v;
        }
    }

    // ========== epoch 1b: convert + write A/B to LDS, zero P ==========
    #pragma unroll
    for (int g = 0; g < 4; ++g) {
        const float4 v0 = e1[2 * g], v1 = e1[2 * g + 1];
        float a8[8] = {v0.x, v0.y, v0.z, v0.w, v1.x, v1.y, v1.z, v1.w};
        v8h hi;
        #pragma unroll
        for (int j = 0; j < 8; ++j) hi[j] = (_Float16)a8[j];
        *(v8h*)(S + B_OFF + swz(r, (q << 2) + g)) = hi;
        if (r >= 96) {                 // lo part of main (fp16 hi/lo split)
            v8h lo;
            #pragma unroll
            for (int j = 0; j < 8; ++j) lo[j] = (_Float16)(a8[j] - (float)hi[j]);
            *(v8h*)(S + ALO_OFF + swz(r - 96, (q << 2) + g)) = lo;
        }
    }
    *(uint4*)(S + P_OFF + tid * 16) = make_uint4(0, 0, 0, 0);

    // convert prefetched V to fp16 (frees 32 regs -> 16 held through epoch 2)
    v8h hv[4];
    #pragma unroll
    for (int i = 0; i < 4; ++i)
        #pragma unroll
        for (int j = 0; j < 8; ++j) hv[i][j] = (_Float16)pv[i][j];

    __syncthreads();

    const int l15 = lane & 15, quad = lane >> 4;
    const int mt  = w >> 2;              // m-tile (16 pixels)
    const int ntp = (w & 3) << 1;        // first of 2 n-tiles

    // ========== epoch 2: L = (A_hi + A_lo) * B^T via MFMA ==========
    {
        const int arow = 96 + (mt << 4) + l15;
        const int lrow = (mt << 4) + l15;
        const int b0r  = (ntp << 4) + l15, b1r = b0r + 16;
        v4f acc0 = {0, 0, 0, 0}, acc1 = {0, 0, 0, 0};
        #pragma unroll
        for (int ks = 0; ks < 4; ++ks) {
            const int c16 = (ks << 2) + quad;
            const v8h ahi = *(const v8h*)(S + B_OFF   + swz(arow, c16));
            const v8h alo = *(const v8h*)(S + ALO_OFF + swz(lrow, c16));
            const v8h bb0 = *(const v8h*)(S + B_OFF   + swz(b0r,  c16));
            const v8h bb1 = *(const v8h*)(S + B_OFF   + swz(b1r,  c16));
            acc0 = __builtin_amdgcn_mfma_f32_16x16x32_f16(ahi, bb0, acc0, 0, 0, 0);
            acc0 = __builtin_amdgcn_mfma_f32_16x16x32_f16(alo, bb0, acc0, 0, 0, 0);
            acc1 = __builtin_amdgcn_mfma_f32_16x16x32_f16(ahi, bb1, acc1, 0, 0, 0);
            acc1 = __builtin_amdgcn_mfma_f32_16x16x32_f16(alo, bb1, acc1, 0, 0, 0);
        }
        // C layout: col = lane&15 (n), row = quad*4 + reg (m)
        #pragma unroll
        for (int j = 0; j < 4; ++j) {
            const int px = (mt << 4) + (quad << 2) + j;
            *(float*)(S + L_OFF + (px << 9) + ((((ntp    ) << 4) + l15) << 2)) = acc0[j];
            *(float*)(S + L_OFF + (px << 9) + ((((ntp + 1) << 4) + l15) << 2)) = acc1[j];
        }
    }
    __syncthreads();

    // ========== epoch 3: VT writes (overwrite B16) + softmax -> P ==========
    {
        #pragma unroll
        for (int i = 0; i < 4; ++i) {
            const int tk = w + (i << 3);
            const int pb = tk & 15;
            const int ch = ((tk >> 4) << 6) + lane;
            *(v8h*)(S + B_OFF + swz(ch, pb)) = hv[i];
        }
        // softmax: 2 pixels per wave-half (butterfly stays within 32 lanes)
        const int half = lane >> 5;
        const int l    = lane & 31;
        #pragma unroll
        for (int i = 0; i < 2; ++i) {
            const int t = (w << 2) + (i << 1) + half;
            const int ty = t >> 3, tx = t & 7;
            const bool act = l < 26;
            int col;
            if (l < 25) {
                const int dy = l / 5 - 2, dx = l % 5 - 2;
                col = (ty + dy + 2) * 12 + (tx + dx + 2);
            } else col = 96 + t;                  // self column
            const float lg = act ? *(const float*)(S + L_OFF + (t << 9) + (col << 2)) : -INFINITY;
            float m = lg;
            #pragma unroll
            for (int off = 16; off; off >>= 1) m = fmaxf(m, __shfl_xor(m, off));
            const float e = act ? __expf(lg - m) : 0.f;
            float s = e;
            #pragma unroll
            for (int off = 16; off; off >>= 1) s += __shfl_xor(s, off);
            if (act)
                *(_Float16*)(S + P_OFF + swz(t, col >> 3) + ((col & 7) << 1)) = (_Float16)(e / s);
        }
    }
    __syncthreads();

    // ========== epoch 4: O = P * V via MFMA, store ==========
    {
        const int prow = (mt << 4) + l15;
        const int v0r  = (ntp << 4) + l15, v1r = v0r + 16;   // VT rows = out channels
        v4f acc0 = {0, 0, 0, 0}, acc1 = {0, 0, 0, 0};
        #pragma unroll
        for (int ks = 0; ks < 4; ++ks) {
            const int c16 = (ks << 2) + quad;
            const v8h pa  = *(const v8h*)(S + P_OFF + swz(prow, c16));
            const v8h vt0 = *(const v8h*)(S + B_OFF + swz(v0r,  c16));
            const v8h vt1 = *(const v8h*)(S + B_OFF + swz(v1r,  c16));
            acc0 = __builtin_amdgcn_mfma_f32_16x16x32_f16(pa, vt0, acc0, 0, 0, 0);
            acc1 = __builtin_amdgcn_mfma_f32_16x16x32_f16(pa, vt1, acc1, 0, 0, 0);
        }
        #pragma unroll
        for (int j = 0; j < 4; ++j) {
            const int px = (mt << 4) + (quad << 2) + j;
            const size_t gbase =
                (size_t)((((b << 6) + h0 + (px >> 3)) << 6) + (w0 + (px & 7))) * 128;
            out[gbase + ((ntp    ) << 4) + l15] = acc0[j];
            out[gbase + ((ntp + 1) << 4) + l15] = acc1[j];
        }
    }
}

extern "C" void kernel_launch(void* const* d_in, const int* in_sizes, int n_in,
                              void* d_out, int out_size, void* d_ws, size_t ws_size,
                              hipStream_t stream) {
    const float* main_      = (const float*)d_in[0];
    const float* main_value = (const float*)d_in[1];
    const float* ref        = (const float*)d_in[2];
    const float* ref_value  = (const float*)d_in[3];
    float* out = (float*)d_out;

    dim3 grid(4 * 16 * 8), block(512);   // 512 blocks (4x8 pixel tiles), 2 blocks/CU
    local_attn_mfma4<<<grid, block, 0, stream>>>(main_, main_value, ref, ref_value, out);
}